// Round 1
// baseline (91.126 us; speedup 1.0000x reference)
//
#include <hip/hip_runtime.h>
#include <math.h>

#define BLOCK 256

// KDE: out[b,m] = (coef/N) * sum_n exp(-0.5*||p_m - x_{b,n}||^2 / h^2)
// Pre-scale coords by rs = sqrt(0.5/(h^2 * ln2)) so the per-pair math is
// exp2(-||p' - x'||^2): sub,sub,mul,fma + v_exp_f32(neg modifier) + acc add.
__global__ __launch_bounds__(BLOCK, 4) void kde_kernel(
    const float* __restrict__ inputs,   // (B, N, 2)
    const float* __restrict__ points,   // (M, 2)
    float* __restrict__ out,            // (B, M), pre-zeroed
    int N, int M, int nPerBlock, float rs, float coefN)
{
    const int b   = blockIdx.y;
    const int n0  = blockIdx.x * nPerBlock;
    const int tid = (int)threadIdx.x;
    const int m0  = tid;
    const int m1  = tid + BLOCK;

    const float2* pts = reinterpret_cast<const float2*>(points);
    float px0 = 0.f, py0 = 0.f, px1 = 0.f, py1 = 0.f;
    const bool has0 = (m0 < M);
    const bool has1 = (m1 < M);
    if (has0) { float2 p = pts[m0]; px0 = p.x * rs; py0 = p.y * rs; }
    if (has1) { float2 p = pts[m1]; px1 = p.x * rs; py1 = p.y * rs; }

    // Per-batch sample row; n and b are wave-uniform -> scalar loads expected.
    const float2* src = reinterpret_cast<const float2*>(inputs) + (size_t)b * N;

    float acc0 = 0.f, acc1 = 0.f;
#pragma unroll 4
    for (int i = 0; i < nPerBlock; ++i) {
        float2 s = src[n0 + i];
        float sx = s.x * rs;
        float sy = s.y * rs;

        float dx0 = px0 - sx, dy0 = py0 - sy;
        float sq0 = fmaf(dy0, dy0, dx0 * dx0);
        float dx1 = px1 - sx, dy1 = py1 - sy;
        float sq1 = fmaf(dy1, dy1, dx1 * dx1);

#if __has_builtin(__builtin_amdgcn_exp2f)
        acc0 += __builtin_amdgcn_exp2f(-sq0);
        acc1 += __builtin_amdgcn_exp2f(-sq1);
#else
        acc0 += exp2f(-sq0);
        acc1 += exp2f(-sq1);
#endif
    }

    if (has0) atomicAdd(&out[(size_t)b * M + m0], acc0 * coefN);
    if (has1) atomicAdd(&out[(size_t)b * M + m1], acc1 * coefN);
}

extern "C" void kernel_launch(void* const* d_in, const int* in_sizes, int n_in,
                              void* d_out, int out_size, void* d_ws, size_t ws_size,
                              hipStream_t stream) {
    const float* inputs = (const float*)d_in[0];   // (B, N, 2) fp32
    const float* points = (const float*)d_in[1];   // (M, 2) fp32
    float* out = (float*)d_out;                    // (B, M) fp32

    const int M = in_sizes[1] / 2;          // 512
    const int B = out_size / M;             // 128
    const int N = in_sizes[0] / (2 * B);    // 2048

    // Silverman bandwidth, d = 2
    const double h    = pow(4.0 / 4.0, 1.0 / 6.0) * pow((double)N, -1.0 / 6.0);
    const double h2   = h * h;
    const double coef = 1.0 / (2.0 * M_PI * h2);
    const double t    = 0.5 / (h2 * M_LN2);       // exp(-0.5*sq/h^2) = exp2(-t*sq)
    const float  rs    = (float)sqrt(t);
    const float  coefN = (float)(coef / (double)N);

    const int NSPLIT = 8;
    const int nPerBlock = N / NSPLIT;       // 256

    hipMemsetAsync(out, 0, (size_t)out_size * sizeof(float), stream);

    dim3 grid(NSPLIT, B);
    kde_kernel<<<grid, BLOCK, 0, stream>>>(inputs, points, out,
                                           N, M, nPerBlock, rs, coefN);
}

// Round 2
// 83.878 us; speedup vs baseline: 1.0864x; 1.0864x over previous
//
#include <hip/hip_runtime.h>
#include <math.h>

#define BLOCK 256
#define NSPLIT 16
#define CHUNK 8

#if __has_builtin(__builtin_amdgcn_exp2f)
#define EXP2F(x) __builtin_amdgcn_exp2f(x)
#else
#define EXP2F(x) exp2f(x)
#endif

// Precompute per-sample constants: a = 2t*sx, b = 2t*sy, c = t*(sx^2+sy^2),
// so that t*||p - s||^2 = (c + q_m) - a*px - b*py with q_m = t*||p||^2.
// SoA layout in d_ws for wide uniform (scalar) loads in the main kernel.
__global__ __launch_bounds__(BLOCK, 8) void prescale_kernel(
    const float* __restrict__ inputs,   // (B*N, 2)
    float* __restrict__ Aarr, float* __restrict__ Barr, float* __restrict__ Carr,
    int total, float t2, float t)
{
    int i = blockIdx.x * BLOCK + (int)threadIdx.x;
    if (i < total) {
        float2 s = reinterpret_cast<const float2*>(inputs)[i];
        Aarr[i] = t2 * s.x;
        Barr[i] = t2 * s.y;
        Carr[i] = t * fmaf(s.x, s.x, s.y * s.y);
    }
}

// out[b,m] = coefN * sum_n exp2(a_n*px + b_n*py - (c_n + q_m))
__global__ __launch_bounds__(BLOCK, 8) void kde_kernel(
    const float* __restrict__ Aarr, const float* __restrict__ Barr,
    const float* __restrict__ Carr,
    const float* __restrict__ points,   // (M, 2)
    float* __restrict__ out,            // (B, M), pre-zeroed
    int N, int M, int nPerBlock, float t, float coefN)
{
    const int b    = blockIdx.y;
    const int base = b * N + blockIdx.x * nPerBlock;
    const int tid  = (int)threadIdx.x;
    const int m0   = tid;
    const int m1   = tid + BLOCK;

    const float2* pts = reinterpret_cast<const float2*>(points);
    float2 p0 = pts[m0 < M ? m0 : 0];
    float2 p1 = pts[m1 < M ? m1 : 0];
    const float q0 = t * fmaf(p0.x, p0.x, p0.y * p0.y);
    const float q1 = t * fmaf(p1.x, p1.x, p1.y * p1.y);

    float acc0 = 0.f, acc1 = 0.f;
    for (int i0 = 0; i0 < nPerBlock; i0 += CHUNK) {
        float av[CHUNK], bv[CHUNK], cv[CHUNK];
#pragma unroll
        for (int j = 0; j < CHUNK; ++j) {
            av[j] = Aarr[base + i0 + j];   // lane-uniform -> s_load, merges wide
            bv[j] = Barr[base + i0 + j];
            cv[j] = Carr[base + i0 + j];
        }
#pragma unroll
        for (int j = 0; j < CHUNK; ++j) {
            float w0 = fmaf(av[j], p0.x, fmaf(bv[j], p0.y, -(cv[j] + q0)));
            float w1 = fmaf(av[j], p1.x, fmaf(bv[j], p1.y, -(cv[j] + q1)));
            acc0 += EXP2F(w0);
            acc1 += EXP2F(w1);
        }
    }

    if (m0 < M) atomicAdd(&out[(size_t)b * M + m0], acc0 * coefN);
    if (m1 < M) atomicAdd(&out[(size_t)b * M + m1], acc1 * coefN);
}

extern "C" void kernel_launch(void* const* d_in, const int* in_sizes, int n_in,
                              void* d_out, int out_size, void* d_ws, size_t ws_size,
                              hipStream_t stream) {
    const float* inputs = (const float*)d_in[0];   // (B, N, 2) fp32
    const float* points = (const float*)d_in[1];   // (M, 2) fp32
    float* out = (float*)d_out;                    // (B, M) fp32

    const int M = in_sizes[1] / 2;          // 512
    const int B = out_size / M;             // 128
    const int N = in_sizes[0] / (2 * B);    // 2048
    const int total = B * N;                // 262144

    // Silverman bandwidth, d = 2
    const double h    = pow(4.0 / 4.0, 1.0 / 6.0) * pow((double)N, -1.0 / 6.0);
    const double h2   = h * h;
    const double coef = 1.0 / (2.0 * M_PI * h2);
    const double td   = 0.5 / (h2 * M_LN2);       // exp(-0.5*sq/h^2) = exp2(-t*sq)
    const float  t     = (float)td;
    const float  t2    = (float)(2.0 * td);
    const float  coefN = (float)(coef / (double)N);

    float* Aarr = (float*)d_ws;
    float* Barr = Aarr + total;
    float* Carr = Barr + total;

    hipMemsetAsync(out, 0, (size_t)out_size * sizeof(float), stream);

    prescale_kernel<<<(total + BLOCK - 1) / BLOCK, BLOCK, 0, stream>>>(
        inputs, Aarr, Barr, Carr, total, t2, t);

    const int nPerBlock = N / NSPLIT;       // 128
    dim3 grid(NSPLIT, B);
    kde_kernel<<<grid, BLOCK, 0, stream>>>(Aarr, Barr, Carr, points, out,
                                           N, M, nPerBlock, t, coefN);
}